// Round 17
// baseline (51.337 us; speedup 1.0000x reference)
//
#include <hip/hip_runtime.h>
#include <math.h>

#define G_ 320
#define N_ 1000
#define T_ 10
#define C_ 96
#define E_ 8000
#define QN 250          // nodes per quarter (4 quarters per graph)
#define NTB 129         // ratio-table points per half (128 intervals)

typedef float float4n __attribute__((ext_vector_type(4)));

// Single fused kernel, no CSR: per-edge LDS float-atomic accumulation of
// (num,den) with no-max softmax (logits bounded ~|3|), then streamed
// non-temporal output expansion. Block = (quarter q, graph g), 256 threads.
// out[g,n,c] = S[g,n]*Wl[c] + (bl[c]+bias[c]+pos[t,c])
// logit(u,v) = 0.6*(u*A+v*B+Cb) + big * tab[which][ratio]   (bl+br==0 path)
__global__ __launch_bounds__(256, 6) void kAll3(
        const float* __restrict__ x, const int* __restrict__ ei,
        const float* __restrict__ Wl, const float* __restrict__ bl,
        const float* __restrict__ Wr, const float* __restrict__ br,
        const float* __restrict__ att, const float* __restrict__ bias,
        float4* __restrict__ out) {
    __shared__ float xgs[N_];
    __shared__ float numS[QN], denS[QN];
    __shared__ float tabL[2 * NTB];
    __shared__ float4 wl4[C_ / 4], cb4[C_ / 4];
    __shared__ float lin4[4];             // 0.6A, 0.6B, 0.6Cb, homog flag

    const int tid = threadIdx.x;
    const int q = blockIdx.x, g = blockIdx.y;
    const int lo = q * QN;
    const int t = g % T_;

    // ---- stage phase (global loads issue first; VALU table work hides) ----
    if (tid < N_ / 4)
        ((float4*)xgs)[tid] = ((const float4*)(x + (size_t)g * N_))[tid];
    if (tid < QN) { numS[tid] = 0.f; denS[tid] = 0.f; }
    if (tid < C_) {                       // expansion tables (wl, bias+pos)
        int k2 = tid & ~1;
        float dt = __expf(-(float)k2 * (logf(10000.0f) / (float)C_));
        float ang = (float)t * dt;
        float pe = (tid & 1) ? cosf(ang) : sinf(ang);
        ((float*)wl4)[tid] = Wl[tid];
        ((float*)cb4)[tid] = bl[tid] + bias[tid] + pe;
    }
    {   // lin terms (waves 0-2) + homogeneity flag (wave 3)
        int w = tid >> 6, lane = tid & 63;
        if (w < 3) {
            float s = 0.f;
            for (int i = lane; i < C_; i += 64) {
                float a = att[i];
                float m = (w == 0) ? Wl[i] : (w == 1) ? Wr[i] : (bl[i] + br[i]);
                s += a * m;
            }
            for (int off = 32; off; off >>= 1) s += __shfl_down(s, off);
            if (lane == 0) lin4[w] = 0.6f * s;
        } else {
            float m = 0.f;
            for (int i = lane; i < C_; i += 64) m = fmaxf(m, fabsf(bl[i] + br[i]));
            for (int off = 32; off; off >>= 1) m = fmaxf(m, __shfl_down(m, off));
            if (lane == 0) lin4[3] = (m == 0.f) ? 1.f : 0.f;
        }
    }
    // ratio tables: tab[0][j]=sum 0.4a|wl + t_j*wr| ; tab[1][j] roles swapped
    for (int i = tid; i < 2 * NTB; i += 256) {
        int which = (i >= NTB);
        int j = i - which * NTB;
        float tt = -1.f + (float)j * (2.f / (float)(NTB - 1));
        float s = 0.f;
        for (int c = 0; c < C_; c++) {     // uniform c -> scalar loads
            float wl = Wl[c], wr = Wr[c];
            float val = which ? fmaf(tt, wl, wr) : fmaf(tt, wr, wl);
            s = fmaf(0.4f * att[c], fabsf(val), s);
        }
        tabL[i] = s;
    }
    __syncthreads();

    // ---- edge pass: no-max softmax accumulation via LDS float atomics ----
    const float la = lin4[0], lb = lin4[1], lc = lin4[2];
    const bool homog = (lin4[3] != 0.f);   // uniform branch
    const int4* d4 = (const int4*)(ei + E_);
    const int4* s4 = (const int4*)ei;
    if (homog) {
        for (int j = tid; j < E_ / 4; j += 256) {
            int4 d = d4[j];
            int4 s = s4[j];
#define ACC(DD, SS) { int r = (DD) - lo;                                     \
            if ((unsigned)r < (unsigned)QN) {                                \
                float uu = xgs[SS], vv = xgs[DD];                            \
                float au = fabsf(uu), av = fabsf(vv);                        \
                bool ub = au >= av;                                          \
                float big = ub ? au : av;                                    \
                float tt = __fdividef(ub ? vv : uu, ub ? uu : vv);           \
                tt = fmaxf(fminf(tt, 1.f), -1.f);                            \
                float fi = fmaf(tt, 64.f, 64.f);                             \
                int i0 = min((int)fi, NTB - 2);                              \
                float fr = fi - (float)i0;                                   \
                int bse = ub ? 0 : NTB;                                      \
                float ta = tabL[bse + i0], tb = tabL[bse + i0 + 1];          \
                float l = fmaf(big, fmaf(fr, tb - ta, ta),                   \
                               fmaf(uu, la, fmaf(vv, lb, lc)));              \
                float e = __expf(l);                                         \
                atomicAdd(&denS[r], e);                                      \
                atomicAdd(&numS[r], e * uu); } }
            ACC(d.x, s.x) ACC(d.y, s.y) ACC(d.z, s.z) ACC(d.w, s.w)
#undef ACC
        }
    } else {
        // exact fallback (bl+br != 0): uniform-c scalar-load channel loop
        for (int j = tid; j < E_ / 4; j += 256) {
            int4 d = d4[j];
            int4 s = s4[j];
#define ACCX(DD, SS) { int r = (DD) - lo;                                    \
            if ((unsigned)r < (unsigned)QN) {                                \
                float uu = xgs[SS], vv = xgs[DD];                            \
                float a2 = 0.f;                                              \
                for (int c = 0; c < C_; c++) {                               \
                    float wv = fmaf(uu, Wl[c], fmaf(vv, Wr[c], bl[c] + br[c]));\
                    a2 = fmaf(0.4f * att[c], fabsf(wv), a2);                 \
                }                                                            \
                float l = fmaf(uu, la, fmaf(vv, lb, lc)) + a2;               \
                float e = __expf(l);                                         \
                atomicAdd(&denS[r], e);                                      \
                atomicAdd(&numS[r], e * uu); } }
            ACCX(d.x, s.x) ACCX(d.y, s.y) ACCX(d.z, s.z) ACCX(d.w, s.w)
#undef ACCX
        }
    }
    __syncthreads();

    // ---- S pass: fold in self-loop, finalize S = num/den (reuse numS) ----
    if (tid < QN) {
        float uu = xgs[lo + tid];
        float l;
        if (homog) {
            l = fmaf(fabsf(uu), tabL[NTB - 1],      // ratio=+1 endpoint
                     fmaf(uu, la + lb, lc));
        } else {
            float a2 = 0.f;
            for (int c = 0; c < C_; c++) {
                float wv = fmaf(uu, Wl[c] + Wr[c], bl[c] + br[c]);
                a2 = fmaf(0.4f * att[c], fabsf(wv), a2);
            }
            l = fmaf(uu, la + lb, lc) + a2;
        }
        float e = __expf(l);
        numS[tid] = (numS[tid] + e * uu) / (denS[tid] + e);
    }
    __syncthreads();

    // ---- streamed expansion: 250x24 float4, non-temporal; incremental i/24 ----
    float4n* out4 = (float4n*)(out + (size_t)(g * N_ + lo) * (C_ / 4));
    int node = tid / 24, c4 = tid % 24;
    for (int i = tid; i < QN * (C_ / 4); i += 256) {
        float s = numS[node];
        float4 wv = wl4[c4], cb = cb4[c4];
        float4n o = { fmaf(s, wv.x, cb.x), fmaf(s, wv.y, cb.y),
                      fmaf(s, wv.z, cb.z), fmaf(s, wv.w, cb.w) };
        __builtin_nontemporal_store(o, &out4[i]);
        int c4n = c4 + 16;                 // 256 = 10*24 + 16
        int carry = (c4n >= 24) ? 1 : 0;
        node += 10 + carry;
        c4 = c4n - (carry ? 24 : 0);
    }
}

extern "C" void kernel_launch(void* const* d_in, const int* in_sizes, int n_in,
                              void* d_out, int out_size, void* d_ws, size_t ws_size,
                              hipStream_t stream) {
    const float* x    = (const float*)d_in[0];
    const int*   ei   = (const int*)d_in[1];
    const float* Wl   = (const float*)d_in[2];
    const float* bl   = (const float*)d_in[3];
    const float* Wr   = (const float*)d_in[4];
    const float* br   = (const float*)d_in[5];
    const float* att  = (const float*)d_in[6];
    const float* bias = (const float*)d_in[7];
    float4* out = (float4*)d_out;

    hipLaunchKernelGGL(kAll3, dim3(4, G_), dim3(256), 0, stream,
                       x, ei, Wl, bl, Wr, br, att, bias, out);
}

// Round 18
// 42.403 us; speedup vs baseline: 1.2107x; 1.2107x over previous
//
#include <hip/hip_runtime.h>
#include <math.h>

#define G_ 320
#define N_ 1000
#define T_ 10
#define C_ 96
#define E_ 8000
#define QN 250          // nodes per quarter (4 quarters per graph)
#define CAP 2816        // slot capacity per quarter (mean ~2250, +14 sigma)
#define NTB 129         // ratio-table points per half (128 intervals)

// R14 structure (best measured: 42.5 us): single fused kernel, one graph-
// quarter per block, in-LDS CSR + ratio-table logits + per-node online
// softmax + streamed expansion. Block = (quarter q, graph g), 256 threads.
// out[g,n,c] = S[g,n]*Wl[c] + (bl[c]+bias[c]+pos[t,c])
// logit(u,v) = 0.6*(u*A+v*B+Cb) + big * tab[which][ratio]   (bl+br==0 path)
__global__ __launch_bounds__(256, 6) void kAll(
        const float* __restrict__ x, const int* __restrict__ ei,
        const float* __restrict__ Wl, const float* __restrict__ bl,
        const float* __restrict__ Wr, const float* __restrict__ br,
        const float* __restrict__ att, const float* __restrict__ bias,
        float4* __restrict__ out) {
    __shared__ float xgs[N_];
    __shared__ int   slots[CAP];          // packed: src | (dst<<16)
    __shared__ int   cnt[256], cur[256], offsL[260];
    __shared__ float tabL[2 * NTB];
    __shared__ float Sloc[QN];
    __shared__ float4 wl4[C_ / 4], cb4[C_ / 4];
    __shared__ float lin4[4];             // 0.6A, 0.6B, 0.6Cb, homog flag

    const int tid = threadIdx.x;
    const int q = blockIdx.x, g = blockIdx.y;
    const int lo = q * QN;
    const int t = g % T_;

    // ---- stage phase (all independent; x loads issue first, VALU hides) ----
    if (tid < N_ / 4)
        ((float4*)xgs)[tid] = ((const float4*)(x + (size_t)g * N_))[tid];
    cnt[tid] = (tid < QN) ? 1 : 0;        // self-loop pre-count
    if (tid < C_) {                       // expansion tables (wl, bias+pos)
        int k2 = tid & ~1;
        float dt = __expf(-(float)k2 * (logf(10000.0f) / (float)C_));
        float ang = (float)t * dt;
        float pe = (tid & 1) ? cosf(ang) : sinf(ang);
        ((float*)wl4)[tid] = Wl[tid];
        ((float*)cb4)[tid] = bl[tid] + bias[tid] + pe;
    }
    {   // lin terms (waves 0-2) + homogeneity flag (wave 3)
        int w = tid >> 6, lane = tid & 63;
        if (w < 3) {
            float s = 0.f;
            for (int i = lane; i < C_; i += 64) {
                float a = att[i];
                float m = (w == 0) ? Wl[i] : (w == 1) ? Wr[i] : (bl[i] + br[i]);
                s += a * m;
            }
            for (int off = 32; off; off >>= 1) s += __shfl_down(s, off);
            if (lane == 0) lin4[w] = 0.6f * s;
        } else {
            float m = 0.f;
            for (int i = lane; i < C_; i += 64) m = fmaxf(m, fabsf(bl[i] + br[i]));
            for (int off = 32; off; off >>= 1) m = fmaxf(m, __shfl_down(m, off));
            if (lane == 0) lin4[3] = (m == 0.f) ? 1.f : 0.f;
        }
    }
    // ratio tables: tab[0][j]=sum 0.4a|wl + t_j*wr| ; tab[1][j] roles swapped
    for (int i = tid; i < 2 * NTB; i += 256) {
        int which = (i >= NTB);
        int j = i - which * NTB;
        float tt = -1.f + (float)j * (2.f / (float)(NTB - 1));
        float s = 0.f;
        for (int c = 0; c < C_; c++) {     // uniform c -> scalar loads
            float wl = Wl[c], wr = Wr[c];
            float val = which ? fmaf(tt, wl, wr) : fmaf(tt, wr, wl);
            s = fmaf(0.4f * att[c], fabsf(val), s);
        }
        tabL[i] = s;
    }
    __syncthreads();

    // ---- count in-range edges ----
    const int4* d4 = (const int4*)(ei + E_);
    const int4* s4 = (const int4*)ei;
    for (int j = tid; j < E_ / 4; j += 256) {
        int4 d = d4[j];
        int r0 = d.x - lo, r1 = d.y - lo, r2 = d.z - lo, r3 = d.w - lo;
        if ((unsigned)r0 < (unsigned)QN) atomicAdd(&cnt[r0], 1);
        if ((unsigned)r1 < (unsigned)QN) atomicAdd(&cnt[r1], 1);
        if ((unsigned)r2 < (unsigned)QN) atomicAdd(&cnt[r2], 1);
        if ((unsigned)r3 < (unsigned)QN) atomicAdd(&cnt[r3], 1);
    }
    __syncthreads();

    // ---- wave-0 shuffle scan over 256 counters (lane owns 4) ----
    if (tid < 64) {
        int b4 = tid * 4;
        int a0 = cnt[b4], a1 = cnt[b4 + 1], a2 = cnt[b4 + 2], a3 = cnt[b4 + 3];
        int s1 = a0 + a1, s2 = s1 + a2, s3 = s2 + a3;
        int pre = s3;
        for (int off = 1; off < 64; off <<= 1) {
            int tv = __shfl_up(pre, off);
            if (tid >= off) pre += tv;
        }
        int base = pre - s3;
        offsL[b4] = base;          cur[b4] = base;
        offsL[b4 + 1] = base + a0; cur[b4 + 1] = base + a0;
        offsL[b4 + 2] = base + s1; cur[b4 + 2] = base + s1;
        offsL[b4 + 3] = base + s2; cur[b4 + 3] = base + s2;
    }
    __syncthreads();

    // ---- scatter packed ids ----
    for (int j = tid; j < E_ / 4; j += 256) {
        int4 d = d4[j];
        int4 s = s4[j];
#define SCAT(DD, SS) { int r = (DD) - lo;                                    \
        if ((unsigned)r < (unsigned)QN) {                                    \
            int pos = atomicAdd(&cur[r], 1);                                 \
            slots[pos] = (SS) | ((DD) << 16); } }
        SCAT(d.x, s.x) SCAT(d.y, s.y) SCAT(d.z, s.z) SCAT(d.w, s.w)
#undef SCAT
    }
    if (tid < QN) {                        // self-loops
        int nid = lo + tid;
        int pos = atomicAdd(&cur[tid], 1);
        slots[pos] = nid | (nid << 16);
    }
    __syncthreads();

    // ---- per-node logits + online softmax (fused) ----
    const float la = lin4[0], lb = lin4[1], lc = lin4[2];
    const bool homog = (lin4[3] != 0.f);   // uniform branch
    if (tid < QN) {
        int a = offsL[tid], b = offsL[tid + 1];
        float m = -INFINITY, den = 0.f, num = 0.f;
        if (homog) {
            for (int p = a; p < b; ++p) {
                int sd = slots[p];
                float uu = xgs[sd & 0xFFFF], vv = xgs[sd >> 16];
                float au = fabsf(uu), av = fabsf(vv);
                bool ub = au >= av;
                float big = ub ? au : av;
                float tt = (ub ? vv : uu) / (ub ? uu : vv);
                tt = fmaxf(fminf(tt, 1.f), -1.f);         // also sanitizes 0/0
                float fi = fmaf(tt, 64.f, 64.f);          // [0,128]
                int i0 = (int)fi; i0 = min(i0, NTB - 2);
                float fr = fi - (float)i0;
                int bse = ub ? 0 : NTB;
                float t0 = tabL[bse + i0], t1 = tabL[bse + i0 + 1];
                float l = fmaf(big, fmaf(fr, t1 - t0, t0),
                               fmaf(uu, la, fmaf(vv, lb, lc)));
                float nm = fmaxf(m, l);
                float sc = __expf(m - nm);
                float ex = __expf(l - nm);
                den = den * sc + ex;
                num = fmaf(ex, uu, num * sc);
                m = nm;
            }
        } else {
            // exact fallback (bl+br != 0): uniform c -> scalar loads
            for (int p = a; p < b; ++p) {
                int sd = slots[p];
                float uu = xgs[sd & 0xFFFF], vv = xgs[sd >> 16];
                float a2 = 0.f;
                for (int c = 0; c < C_; c++) {
                    float wv = fmaf(uu, Wl[c], fmaf(vv, Wr[c], bl[c] + br[c]));
                    a2 = fmaf(0.4f * att[c], fabsf(wv), a2);
                }
                float l = fmaf(uu, la, fmaf(vv, lb, lc)) + a2;
                float nm = fmaxf(m, l);
                float sc = __expf(m - nm);
                float ex = __expf(l - nm);
                den = den * sc + ex;
                num = fmaf(ex, uu, num * sc);
                m = nm;
            }
        }
        Sloc[tid] = num / den;
    }
    __syncthreads();

    // ---- streamed expansion: 250x24 float4, coalesced; incremental i/24 ----
    float4* out4 = out + (size_t)(g * N_ + lo) * (C_ / 4);
    int node = tid / 24, c4 = tid % 24;
    for (int i = tid; i < QN * (C_ / 4); i += 256) {
        float s = Sloc[node];
        float4 wv = wl4[c4], cb = cb4[c4];
        out4[i] = make_float4(fmaf(s, wv.x, cb.x), fmaf(s, wv.y, cb.y),
                              fmaf(s, wv.z, cb.z), fmaf(s, wv.w, cb.w));
        int c4n = c4 + 16;                 // 256 = 10*24 + 16
        int carry = (c4n >= 24) ? 1 : 0;
        node += 10 + carry;
        c4 = c4n - (carry ? 24 : 0);
    }
}

extern "C" void kernel_launch(void* const* d_in, const int* in_sizes, int n_in,
                              void* d_out, int out_size, void* d_ws, size_t ws_size,
                              hipStream_t stream) {
    const float* x    = (const float*)d_in[0];
    const int*   ei   = (const int*)d_in[1];
    const float* Wl   = (const float*)d_in[2];
    const float* bl   = (const float*)d_in[3];
    const float* Wr   = (const float*)d_in[4];
    const float* br   = (const float*)d_in[5];
    const float* att  = (const float*)d_in[6];
    const float* bias = (const float*)d_in[7];
    float4* out = (float4*)d_out;

    hipLaunchKernelGGL(kAll, dim3(4, G_), dim3(256), 0, stream,
                       x, ei, Wl, bl, Wr, br, att, bias, out);
}